// Round 4
// baseline (433.507 us; speedup 1.0000x reference)
//
#include <hip/hip_runtime.h>
#include <stdint.h>

typedef short bf16x8_t __attribute__((ext_vector_type(8)));
typedef short bf16x4_t __attribute__((ext_vector_type(4)));
typedef float f32x4_t __attribute__((ext_vector_type(4)));
typedef unsigned short u16x4_t __attribute__((ext_vector_type(4)));
typedef unsigned short u16x8_t __attribute__((ext_vector_type(8)));

#define DEV static __device__ __forceinline__

DEV float bf2f(unsigned short u) {
  union { unsigned int i; float f; } v; v.i = ((unsigned int)u) << 16; return v.f;
}
DEV unsigned short f2bf(float f) {
  union { float f; unsigned int i; } v; v.f = f;
  unsigned int x = v.i;
  unsigned int lsb = (x >> 16) & 1u;
  x += 0x7fffu + lsb;
  return (unsigned short)(x >> 16);
}

// Up to 3 cvt segments; boundaries in blocks (block-uniform).
struct CvtSeg {
  const float* src[3];
  unsigned short* dst[3];
  int bstart[4];   // bstart[0]=0; bstart[3]=total blocks
};

DEV void cvt_block(const CvtSeg& cs, int vb, int tid) {   // 256-thread variant
  int seg = (vb >= cs.bstart[1] ? 1 : 0) + (vb >= cs.bstart[2] ? 1 : 0);
  int local = (vb - cs.bstart[seg]) * 256 + tid;
  float4 v = ((const float4*)cs.src[seg])[local];
  u16x4_t o = { f2bf(v.x), f2bf(v.y), f2bf(v.z), f2bf(v.w) };
  *(u16x4_t*)&cs.dst[seg][local * 4] = o;
}

DEV void cvt_block512(const CvtSeg& cs, int vb, int tid) { // 512-thread variant
  int seg = (vb >= cs.bstart[1] ? 1 : 0) + (vb >= cs.bstart[2] ? 1 : 0);
  int local = (vb - cs.bstart[seg]) * 512 + tid;
  float4 v = ((const float4*)cs.src[seg])[local];
  u16x4_t o = { f2bf(v.x), f2bf(v.y), f2bf(v.z), f2bf(v.w) };
  *(u16x4_t*)&cs.dst[seg][local * 4] = o;
}

// ---------------------------------------------------------------------------
// Dispatch 1: convert Wm0 + U0 only (critical path for xu_fused / hyper-0)
__global__ __launch_bounds__(256) void k_cvt(CvtSeg cs) {
  cvt_block(cs, blockIdx.x, threadIdx.x);
}

// ---------------------------------------------------------------------------
// xu_fused: converts x (fp32 -> bf16 in xb) AND computes u0 = x @ U0^T.
__global__ __launch_bounds__(256, 2) void xu_fused(
    const float* __restrict__ x,            // [8192 x 1024] fp32
    const unsigned short* __restrict__ U0,  // [64 x 1024] bf16
    unsigned short* __restrict__ xb,        // [8192 x 1024] bf16 out
    unsigned short* __restrict__ u_out) {   // [8192 x 64] bf16 out
  __shared__ unsigned short tlds[4 * 16 * 72];  // per-wave x chunk [16][72]
  __shared__ float upart[4 * 16 * 68];          // per-wave u partial [16][68]

  const int tid = threadIdx.x;
  const int lane = tid & 63;
  const int w = tid >> 6;
  const int fr = lane & 15;
  const int quad = lane >> 4;
  const int rowBase = blockIdx.x * 16;

  unsigned short* tl = &tlds[w * 16 * 72];
  const int m2 = lane >> 2;          // row within the 16-row block
  const int kc = (lane & 3) * 16;    // 16-col sub-chunk

  f32x4_t uacc[4];
#pragma unroll
  for (int n = 0; n < 4; n++) uacc[n] = f32x4_t{0.f, 0.f, 0.f, 0.f};

  for (int it = 0; it < 4; ++it) {
    const int cb = w * 256 + it * 64;  // k-chunk base

    {
      const float* xp = x + (size_t)(rowBase + m2) * 1024 + cb + kc;
      float4 v0 = *(const float4*)(xp);
      float4 v1 = *(const float4*)(xp + 4);
      float4 v2 = *(const float4*)(xp + 8);
      float4 v3 = *(const float4*)(xp + 12);
      u16x8_t o0 = { f2bf(v0.x), f2bf(v0.y), f2bf(v0.z), f2bf(v0.w),
                     f2bf(v1.x), f2bf(v1.y), f2bf(v1.z), f2bf(v1.w) };
      u16x8_t o1 = { f2bf(v2.x), f2bf(v2.y), f2bf(v2.z), f2bf(v2.w),
                     f2bf(v3.x), f2bf(v3.y), f2bf(v3.z), f2bf(v3.w) };
      *(u16x8_t*)&tl[m2 * 72 + kc] = o0;
      *(u16x8_t*)&tl[m2 * 72 + kc + 8] = o1;
      unsigned short* xo = xb + (size_t)(rowBase + m2) * 1024 + cb + kc;
      *(u16x8_t*)xo = o0;
      *(u16x8_t*)(xo + 8) = o1;
    }

#pragma unroll
    for (int ks = 0; ks < 2; ++ks) {
      bf16x8_t at = *(const bf16x8_t*)&tl[fr * 72 + ks * 32 + quad * 8];
#pragma unroll
      for (int n = 0; n < 4; n++) {
        bf16x8_t bu = *(const bf16x8_t*)&U0[(size_t)(n * 16 + fr) * 1024 + cb +
                                            ks * 32 + quad * 8];
        uacc[n] = __builtin_amdgcn_mfma_f32_16x16x32_bf16(at, bu, uacc[n], 0, 0, 0);
      }
    }
  }

  {
    float* up = &upart[w * 16 * 68];
#pragma unroll
    for (int n = 0; n < 4; n++)
#pragma unroll
      for (int r = 0; r < 4; r++)
        up[(quad * 4 + r) * 68 + n * 16 + fr] = uacc[n][r];
  }
  __syncthreads();
  {
    int m = tid >> 4;
    int c0 = (tid & 15) * 4;
    f32x4_t s = {0.f, 0.f, 0.f, 0.f};
#pragma unroll
    for (int wv = 0; wv < 4; wv++)
      s += *(const f32x4_t*)&upart[wv * 16 * 68 + m * 68 + c0];
    u16x4_t o = { f2bf(s[0]), f2bf(s[1]), f2bf(s[2]), f2bf(s[3]) };
    *(u16x4_t*)&u_out[(size_t)(rowBase + m) * 64 + c0] = o;
  }
}

// ---------------------------------------------------------------------------
// Fused hyper-GEMM + per-sample contraction, 256x256 tile, BK=32, 8 waves,
// 4-slot LDS ring (depth-2 prefetch => genuinely counted vmcnt(4), the load
// queue never drains in the main loop).
// Per tile: 12 ds_read_b128 + 4 GLD (tile t+2) + 32 MFMA + vmcnt(4).
// LDS: [4 slots][256 rows][32 cols] shorts (64B rows). Conflict-free XOR:
//   stored slot sl = quad ^ ((fr>>1)&3)  (2 lanes per 16B granule = free),
//   inverse-permuted GLD source chunk c = (lane&3) ^ ((lane>>3)&3).
// Appended cvt blocks (blockIdx.x >= 512) convert the NEXT layer's weights.
#define GLD(gp, lp)                                              \
  __builtin_amdgcn_global_load_lds(                              \
      (const __attribute__((address_space(1))) void*)(gp),       \
      (__attribute__((address_space(3))) void*)(lp), 16, 0, 0)

__global__ __launch_bounds__(512, 1) void k_hyper(
    const unsigned short* __restrict__ A,    // [8192 x 1024] bf16
    const unsigned short* __restrict__ Wmb,  // [4096 x 1024] bf16
    const unsigned short* __restrict__ ug,   // [8192 x 64] bf16
    const float* __restrict__ bm,            // [4096] fp32
    unsigned short* __restrict__ h_out,      // [8192 x 64] bf16
    CvtSeg cs) {
  __shared__ unsigned short lds[65536];      // 128 KiB

  if (blockIdx.x >= 512) {                   // appended conversion work
    cvt_block512(cs, blockIdx.x - 512, threadIdx.x);
    return;
  }

  unsigned short* As = lds;                  // [4][256][32]
  unsigned short* Bs = lds + 32768;          // [4][256][32]

  const int tid = threadIdx.x;
  const int lane = tid & 63;
  const int w = tid >> 6;        // wave 0..7
  const int wr = w >> 2;         // 0..1  M-half
  const int wc = w & 3;          // 0..3  N-quarter
  const int bx = blockIdx.x & 15;
  const int by = blockIdx.x >> 4;
  const int rowBase = by * 256;
  const int colBase = bx * 256;
  const int fr = lane & 15;
  const int quad = lane >> 4;

  // --- staging addresses (inverse of the read XOR) ---
  const int lr = lane >> 2;                       // row 0..15 in 16-row chunk
  const int c = (lane & 3) ^ ((lane >> 3) & 3);   // global 8-elem chunk
  const unsigned short* gA0 =
      A + (size_t)(rowBase + w * 16 + lr) * 1024 + c * 8;
  const unsigned short* gA1 = gA0 + (size_t)128 * 1024;
  const int ct0 = colBase + w * 16 + lr;
  const int ct1 = ct0 + 128;
  const unsigned short* gB0 =
      Wmb + (size_t)(((ct0 & 63) << 6) | (ct0 >> 6)) * 1024 + c * 8;
  const unsigned short* gB1 =
      Wmb + (size_t)(((ct1 & 63) << 6) | (ct1 >> 6)) * 1024 + c * 8;
  const int dA0 = w * 512;                        // LDS dest (shorts)
  const int dA1 = 4096 + w * 512;

#define STAGE(t) do { const int sb_ = ((t) & 3) * 8192;              \
    GLD(gA0 + (t) * 32, &As[sb_ + dA0]);                             \
    GLD(gA1 + (t) * 32, &As[sb_ + dA1]);                             \
    GLD(gB0 + (t) * 32, &Bs[sb_ + dA0]);                             \
    GLD(gB1 + (t) * 32, &Bs[sb_ + dA1]); } while (0)

  // --- swizzled ds_read bases (shorts) ---
  const int sl = (quad ^ ((fr >> 1) & 3)) * 8;
  const int aBase = (wr * 128 + fr) * 32 + sl;    // + i*512
  const int bBase = (wc * 64 + fr) * 32 + sl;     // + j*512

  f32x4_t acc[8][4];
#pragma unroll
  for (int i = 0; i < 8; i++)
#pragma unroll
    for (int j = 0; j < 4; j++) acc[i][j] = f32x4_t{0.f, 0.f, 0.f, 0.f};

  // prologue: tiles 0,1 issued; wait tile0 only (vmcnt counts newest 4)
  STAGE(0); STAGE(1);
  asm volatile("s_waitcnt vmcnt(4)" ::: "memory");
  __builtin_amdgcn_s_barrier();

#pragma unroll 4
  for (int t = 0; t < 32; ++t) {
    const int d = (t & 3) * 8192;
    bf16x8_t a[8], b[4];
#pragma unroll
    for (int i = 0; i < 8; i++)
      a[i] = *(const bf16x8_t*)&As[d + aBase + i * 512];
#pragma unroll
    for (int j = 0; j < 4; j++)
      b[j] = *(const bf16x8_t*)&Bs[d + bBase + j * 512];
    if (t < 30) STAGE(t + 2);   // slot (t+2)&3 last read at tile t-2: safe
    __builtin_amdgcn_s_barrier();
    asm volatile("s_waitcnt lgkmcnt(0)" ::: "memory");
    __builtin_amdgcn_sched_barrier(0);
    __builtin_amdgcn_s_setprio(1);
#pragma unroll
    for (int i = 0; i < 8; i++)
#pragma unroll
      for (int j = 0; j < 4; j++)
        acc[i][j] = __builtin_amdgcn_mfma_f32_16x16x32_bf16(a[i], b[j],
                                                            acc[i][j], 0, 0, 0);
    __builtin_amdgcn_s_setprio(0);
    // counted wait: t+1's 4 loads land; t+2's 4 stay in flight across the
    // barrier (queue never drains until the tail).
    if (t < 30) { asm volatile("s_waitcnt vmcnt(4)" ::: "memory"); }
    else if (t == 30) { asm volatile("s_waitcnt vmcnt(0)" ::: "memory"); }
    __builtin_amdgcn_s_barrier();
  }

  // ---- fused contraction epilogue (verified rounds 1-3) ----
  __syncthreads();

  // stage u transposed: u_t[r 0..63][row 0..255], stride 264 to spread banks
  {
    int row = tid >> 1;
    int c0 = (tid & 1) * 32;
    const unsigned short* up = ug + (size_t)(rowBase + row) * 64 + c0;
    bf16x8_t v0 = *(const bf16x8_t*)(up);
    bf16x8_t v1 = *(const bf16x8_t*)(up + 8);
    bf16x8_t v2 = *(const bf16x8_t*)(up + 16);
    bf16x8_t v3 = *(const bf16x8_t*)(up + 24);
#pragma unroll
    for (int m = 0; m < 8; m++) {
      lds[(c0 + m) * 264 + row] = (unsigned short)v0[m];
      lds[(c0 + 8 + m) * 264 + row] = (unsigned short)v1[m];
      lds[(c0 + 16 + m) * 264 + row] = (unsigned short)v2[m];
      lds[(c0 + 24 + m) * 264 + row] = (unsigned short)v3[m];
    }
  }
  __syncthreads();

  const int s = bx * 4 + wc;
  float bmv[4];
#pragma unroll
  for (int j = 0; j < 4; j++) bmv[j] = bm[(j * 16 + fr) * 64 + s];

#pragma unroll
  for (int i = 0; i < 8; i++) {
    int row0 = wr * 128 + i * 16 + quad * 4;
    bf16x4_t uv[4];
#pragma unroll
    for (int j = 0; j < 4; j++)
      uv[j] = *(const bf16x4_t*)&lds[(j * 16 + fr) * 264 + row0];
#pragma unroll
    for (int r = 0; r < 4; r++) {
      float p = 0.f;
#pragma unroll
      for (int j = 0; j < 4; j++)
        p += bf2f((unsigned short)uv[j][r]) * (acc[i][j][r] + bmv[j]);
      p += __shfl_xor(p, 1, 64);
      p += __shfl_xor(p, 2, 64);
      p += __shfl_xor(p, 4, 64);
      p += __shfl_xor(p, 8, 64);
      if (fr == 0)
        h_out[(size_t)(rowBase + row0 + r) * 64 + s] = f2bf(p);
    }
  }
}

// ---------------------------------------------------------------------------
// Fused V-GEMM + next-layer u-GEMM (r4-proven).
__global__ __launch_bounds__(256, 2) void vu_fused(
    const unsigned short* __restrict__ h,    // [8192 x 64] bf16
    const unsigned short* __restrict__ Vb,   // [1024 x 64] bf16
    const float* __restrict__ bias,          // [1024] fp32
    const unsigned short* __restrict__ Un,   // [64 x 1024] bf16 (next U)
    unsigned short* __restrict__ act,        // [8192 x 1024] bf16
    unsigned short* __restrict__ u_out) {    // [8192 x 64] bf16
  __shared__ unsigned short tlds[4 * 16 * 72];
  __shared__ float upart[4 * 16 * 68];

  const int tid = threadIdx.x;
  const int lane = tid & 63;
  const int w = tid >> 6;
  const int fr = lane & 15;
  const int quad = lane >> 4;
  const int rowBase = blockIdx.x * 16;

  unsigned short* tl = &tlds[w * 16 * 72];

  bf16x8_t ah0 = *(const bf16x8_t*)&h[(size_t)(rowBase + fr) * 64 + quad * 8];
  bf16x8_t ah1 = *(const bf16x8_t*)&h[(size_t)(rowBase + fr) * 64 + 32 + quad * 8];

  f32x4_t uacc[4];
#pragma unroll
  for (int n = 0; n < 4; n++) uacc[n] = f32x4_t{0.f, 0.f, 0.f, 0.f};

  for (int it = 0; it < 4; ++it) {
    const int cb = w * 256 + it * 64;

    f32x4_t tacc[4];
#pragma unroll
    for (int nt = 0; nt < 4; nt++) {
      const unsigned short* vrow = Vb + (size_t)(cb + nt * 16 + fr) * 64;
      bf16x8_t b0 = *(const bf16x8_t*)&vrow[quad * 8];
      bf16x8_t b1 = *(const bf16x8_t*)&vrow[32 + quad * 8];
      f32x4_t z = {0.f, 0.f, 0.f, 0.f};
      z = __builtin_amdgcn_mfma_f32_16x16x32_bf16(ah0, b0, z, 0, 0, 0);
      tacc[nt] = __builtin_amdgcn_mfma_f32_16x16x32_bf16(ah1, b1, z, 0, 0, 0);
    }

#pragma unroll
    for (int nt = 0; nt < 4; nt++) {
      float bv = bias[cb + nt * 16 + fr];
#pragma unroll
      for (int r = 0; r < 4; r++) {
        float v = tacc[nt][r] + bv;
        v = v > 0.f ? v : 0.f;
        tl[(quad * 4 + r) * 72 + nt * 16 + fr] = f2bf(v);
      }
    }

    {
      int m2 = lane >> 2;
      int kc = (lane & 3) * 16;
      bf16x8_t t0 = *(const bf16x8_t*)&tl[m2 * 72 + kc];
      bf16x8_t t1 = *(const bf16x8_t*)&tl[m2 * 72 + kc + 8];
      unsigned short* ap = act + (size_t)(rowBase + m2) * 1024 + cb + kc;
      *(bf16x8_t*)ap = t0;
      *(bf16x8_t*)(ap + 8) = t1;
    }

#pragma unroll
    for (int ks = 0; ks < 2; ++ks) {
      bf16x8_t at = *(const bf16x8_t*)&tl[fr * 72 + ks * 32 + quad * 8];
#pragma unroll
      for (int n = 0; n < 4; n++) {
        bf16x8_t bu = *(const bf16x8_t*)&Un[(size_t)(n * 16 + fr) * 1024 + cb +
                                            ks * 32 + quad * 8];
        uacc[n] = __builtin_amdgcn_mfma_f32_16x16x32_bf16(at, bu, uacc[n], 0, 0, 0);
      }
    }
  }

  {
    float* up = &upart[w * 16 * 68];
#pragma unroll
    for (int n = 0; n < 4; n++)
#pragma unroll
      for (int r = 0; r < 4; r++)
        up[(quad * 4 + r) * 68 + n * 16 + fr] = uacc[n][r];
  }
  __syncthreads();
  {
    int m = tid >> 4;
    int c0 = (tid & 15) * 4;
    f32x4_t s = {0.f, 0.f, 0.f, 0.f};
#pragma unroll
    for (int wv = 0; wv < 4; wv++)
      s += *(const f32x4_t*)&upart[wv * 16 * 68 + m * 68 + c0];
    u16x4_t o = { f2bf(s[0]), f2bf(s[1]), f2bf(s[2]), f2bf(s[3]) };
    *(u16x4_t*)&u_out[(size_t)(rowBase + m) * 64 + c0] = o;
  }
}

// ---------------------------------------------------------------------------
// Final layer: out = h @ V^T + b (fp32), K = 64.
__global__ __launch_bounds__(256, 2) void k_final(
    const unsigned short* __restrict__ A, const unsigned short* __restrict__ B,
    const float* __restrict__ bias, float* __restrict__ Cout) {
  __shared__ unsigned short As[128 * 64];
  __shared__ unsigned short Bs[128 * 64];

  const int tid = threadIdx.x;
  const int lane = tid & 63;
  const int w = tid >> 6;
  const int wrow0 = (w & 1) * 64;
  const int wcol0 = (w >> 1) * 64;
  const int rowBase = blockIdx.y * 128;
  const int colBase = blockIdx.x * 128;

  const int rl = lane >> 3;
  const int kbg = (lane & 7) ^ rl;
  const int fr = lane & 15;
  const int quad = lane >> 4;

  f32x4_t acc[4][4];
#pragma unroll
  for (int i = 0; i < 4; i++)
#pragma unroll
    for (int j = 0; j < 4; j++) acc[i][j] = f32x4_t{0.f, 0.f, 0.f, 0.f};

  __syncthreads();
#pragma unroll
  for (int jj = 0; jj < 4; ++jj) {
    int tr = w * 32 + jj * 8 + rl;
    const unsigned short* ga = A + (size_t)(rowBase + tr) * 64 + kbg * 8;
    const unsigned short* gb = B + (size_t)(colBase + tr) * 64 + kbg * 8;
    __builtin_amdgcn_global_load_lds(
        (const __attribute__((address_space(1))) void*)ga,
        (__attribute__((address_space(3))) void*)&As[(w * 32 + jj * 8) * 64],
        16, 0, 0);
    __builtin_amdgcn_global_load_lds(
        (const __attribute__((address_space(1))) void*)gb,
        (__attribute__((address_space(3))) void*)&Bs[(w * 32 + jj * 8) * 64],
        16, 0, 0);
  }
  __syncthreads();

#pragma unroll
  for (int ks = 0; ks < 2; ++ks) {
    bf16x8_t a[4], b[4];
#pragma unroll
    for (int i = 0; i < 4; i++) {
      int m = wrow0 + i * 16 + fr;
      int slot = (ks * 4 + quad) ^ (m & 7);
      a[i] = *(const bf16x8_t*)&As[m * 64 + slot * 8];
    }
#pragma unroll
    for (int j = 0; j < 4; j++) {
      int n = wcol0 + j * 16 + fr;
      int slot = (ks * 4 + quad) ^ (n & 7);
      b[j] = *(const bf16x8_t*)&Bs[n * 64 + slot * 8];
    }
#pragma unroll
    for (int i = 0; i < 4; i++)
#pragma unroll
      for (int j = 0; j < 4; j++)
        acc[i][j] = __builtin_amdgcn_mfma_f32_16x16x32_bf16(a[i], b[j],
                                                            acc[i][j], 0, 0, 0);
  }

#pragma unroll
  for (int j = 0; j < 4; j++) {
    int col = colBase + wcol0 + j * 16 + fr;
    float bv = bias[col];
#pragma unroll
    for (int i = 0; i < 4; i++) {
#pragma unroll
      for (int r = 0; r < 4; r++) {
        int row = rowBase + wrow0 + i * 16 + quad * 4 + r;
        Cout[(size_t)row * 1024 + col] = acc[i][j][r] + bv;
      }
    }
  }
}

// ---------------------------------------------------------------------------
extern "C" void kernel_launch(void* const* d_in, const int* in_sizes, int n_in,
                              void* d_out, int out_size, void* d_ws,
                              size_t ws_size, hipStream_t stream) {
  const float* x = (const float*)d_in[0];
  const float* Wm[3] = {(const float*)d_in[1], (const float*)d_in[6], (const float*)d_in[11]};
  const float* bm[3] = {(const float*)d_in[2], (const float*)d_in[7], (const float*)d_in[12]};
  const float* U[3]  = {(const float*)d_in[3], (const float*)d_in[8], (const float*)d_in[13]};
  const float* V[3]  = {(const float*)d_in[4], (const float*)d_in[9], (const float*)d_in[14]};
  const float* bs[3] = {(const float*)d_in[5], (const float*)d_in[10], (const float*)d_in[15]};

  char* p = (char*)d_ws;
  unsigned short* xb = (unsigned short*)p;  p += 8192UL * 1024 * 2;
  unsigned short* act = (unsigned short*)p; p += 8192UL * 1024 * 2;
  unsigned short* Wmb[3];
  for (int l = 0; l < 3; l++) { Wmb[l] = (unsigned short*)p; p += 4096UL * 1024 * 2; }
  unsigned short* Ub[3];
  for (int l = 0; l < 3; l++) { Ub[l] = (unsigned short*)p; p += 64UL * 1024 * 2; }
  unsigned short* Vb[3];
  for (int l = 0; l < 3; l++) { Vb[l] = (unsigned short*)p; p += 1024UL * 64 * 2; }
  unsigned short* hb = (unsigned short*)p;  p += 8192UL * 64 * 2;
  unsigned short* ug = (unsigned short*)p;  p += 8192UL * 64 * 2;

  // Dispatch 1: convert Wm0 + U0 (38 MB read) — the only serial conversions
  CvtSeg c0;
  c0.src[0] = Wm[0]; c0.dst[0] = Wmb[0];
  c0.src[1] = U[0];  c0.dst[1] = Ub[0];
  c0.src[2] = U[0];  c0.dst[2] = Ub[0];   // unused (bstart collapse)
  c0.bstart[0] = 0; c0.bstart[1] = 4096; c0.bstart[2] = 4160; c0.bstart[3] = 4160;
  k_cvt<<<4160, 256, 0, stream>>>(c0);

  // Dispatch 2: x cvt + u0 = x @ U0^T, fused (writes xb and ug)
  xu_fused<<<512, 256, 0, stream>>>(x, Ub[0], xb, ug);

  // cvt tables for the work appended to each hyper dispatch (512-thread blocks)
  CvtSeg ch[3];
  ch[0].src[0] = Wm[1]; ch[0].dst[0] = Wmb[1];
  ch[0].src[1] = U[1];  ch[0].dst[1] = Ub[1];
  ch[0].src[2] = V[0];  ch[0].dst[2] = Vb[0];
  ch[0].bstart[0] = 0; ch[0].bstart[1] = 2048; ch[0].bstart[2] = 2080; ch[0].bstart[3] = 2112;
  ch[1].src[0] = Wm[2]; ch[1].dst[0] = Wmb[2];
  ch[1].src[1] = U[2];  ch[1].dst[1] = Ub[2];
  ch[1].src[2] = V[1];  ch[1].dst[2] = Vb[1];
  ch[1].bstart[0] = 0; ch[1].bstart[1] = 2048; ch[1].bstart[2] = 2080; ch[1].bstart[3] = 2112;
  ch[2].src[0] = V[2]; ch[2].dst[0] = Vb[2];
  ch[2].src[1] = V[2]; ch[2].dst[1] = Vb[2];   // unused
  ch[2].src[2] = V[2]; ch[2].dst[2] = Vb[2];   // unused
  ch[2].bstart[0] = 0; ch[2].bstart[1] = 32; ch[2].bstart[2] = 32; ch[2].bstart[3] = 32;

  const int hyperGrid[3] = {512 + 2112, 512 + 2112, 512 + 32};

  const unsigned short* cur = xb;
  for (int l = 0; l < 3; l++) {
    // fused: h = einsum('br,brs->bs', u, cur@Wm^T + bm)  [+ appended cvt]
    k_hyper<<<hyperGrid[l], 512, 0, stream>>>(cur, Wmb[l], ug, bm[l], hb, ch[l]);
    if (l < 2) {
      // act = relu(h@V^T + b); u(next) = act @ U[l+1]^T
      vu_fused<<<512, 256, 0, stream>>>(hb, Vb[l], bs[l], Ub[l + 1], act, ug);
      cur = act;
    } else {
      k_final<<<dim3(8, 64), 256, 0, stream>>>(hb, Vb[2], bs[2], (float*)d_out);
    }
  }
}

// Round 5
// 429.038 us; speedup vs baseline: 1.0104x; 1.0104x over previous
//
#include <hip/hip_runtime.h>
#include <stdint.h>

typedef short bf16x8_t __attribute__((ext_vector_type(8)));
typedef short bf16x4_t __attribute__((ext_vector_type(4)));
typedef float f32x4_t __attribute__((ext_vector_type(4)));
typedef unsigned short u16x4_t __attribute__((ext_vector_type(4)));
typedef unsigned short u16x8_t __attribute__((ext_vector_type(8)));

#define DEV static __device__ __forceinline__

DEV float bf2f(unsigned short u) {
  union { unsigned int i; float f; } v; v.i = ((unsigned int)u) << 16; return v.f;
}
DEV unsigned short f2bf(float f) {
  union { float f; unsigned int i; } v; v.f = f;
  unsigned int x = v.i;
  unsigned int lsb = (x >> 16) & 1u;
  x += 0x7fffu + lsb;
  return (unsigned short)(x >> 16);
}

// Up to 3 cvt segments; boundaries in blocks of 256 vec4s (block-uniform).
struct CvtSeg {
  const float* src[3];
  unsigned short* dst[3];
  int bstart[4];   // bstart[0]=0; bstart[3]=total blocks
};

DEV void cvt_block(const CvtSeg& cs, int vb, int tid) {
  int seg = (vb >= cs.bstart[1] ? 1 : 0) + (vb >= cs.bstart[2] ? 1 : 0);
  int local = (vb - cs.bstart[seg]) * 256 + tid;
  float4 v = ((const float4*)cs.src[seg])[local];
  u16x4_t o = { f2bf(v.x), f2bf(v.y), f2bf(v.z), f2bf(v.w) };
  *(u16x4_t*)&cs.dst[seg][local * 4] = o;
}

// ---------------------------------------------------------------------------
// Dispatch 1: convert Wm0 + U0 only (critical path for xu_fused / hyper-0)
__global__ __launch_bounds__(256) void k_cvt(CvtSeg cs) {
  cvt_block(cs, blockIdx.x, threadIdx.x);
}

// ---------------------------------------------------------------------------
// xu_fused: converts x (fp32 -> bf16 in xb) AND computes u0 = x @ U0^T.
__global__ __launch_bounds__(256, 2) void xu_fused(
    const float* __restrict__ x,            // [8192 x 1024] fp32
    const unsigned short* __restrict__ U0,  // [64 x 1024] bf16
    unsigned short* __restrict__ xb,        // [8192 x 1024] bf16 out
    unsigned short* __restrict__ u_out) {   // [8192 x 64] bf16 out
  __shared__ unsigned short tlds[4 * 16 * 72];  // per-wave x chunk [16][72]
  __shared__ float upart[4 * 16 * 68];          // per-wave u partial [16][68]

  const int tid = threadIdx.x;
  const int lane = tid & 63;
  const int w = tid >> 6;
  const int fr = lane & 15;
  const int quad = lane >> 4;
  const int rowBase = blockIdx.x * 16;

  unsigned short* tl = &tlds[w * 16 * 72];
  const int m2 = lane >> 2;          // row within the 16-row block
  const int kc = (lane & 3) * 16;    // 16-col sub-chunk

  f32x4_t uacc[4];
#pragma unroll
  for (int n = 0; n < 4; n++) uacc[n] = f32x4_t{0.f, 0.f, 0.f, 0.f};

  for (int it = 0; it < 4; ++it) {
    const int cb = w * 256 + it * 64;  // k-chunk base

    // load x[16][64] fp32 chunk, convert, stage to LDS + store xb
    {
      const float* xp = x + (size_t)(rowBase + m2) * 1024 + cb + kc;
      float4 v0 = *(const float4*)(xp);
      float4 v1 = *(const float4*)(xp + 4);
      float4 v2 = *(const float4*)(xp + 8);
      float4 v3 = *(const float4*)(xp + 12);
      u16x8_t o0 = { f2bf(v0.x), f2bf(v0.y), f2bf(v0.z), f2bf(v0.w),
                     f2bf(v1.x), f2bf(v1.y), f2bf(v1.z), f2bf(v1.w) };
      u16x8_t o1 = { f2bf(v2.x), f2bf(v2.y), f2bf(v2.z), f2bf(v2.w),
                     f2bf(v3.x), f2bf(v3.y), f2bf(v3.z), f2bf(v3.w) };
      *(u16x8_t*)&tl[m2 * 72 + kc] = o0;
      *(u16x8_t*)&tl[m2 * 72 + kc + 8] = o1;
      unsigned short* xo = xb + (size_t)(rowBase + m2) * 1024 + cb + kc;
      *(u16x8_t*)xo = o0;
      *(u16x8_t*)(xo + 8) = o1;
    }

    // u += x_chunk @ U0^T (K = this 64-col chunk)
#pragma unroll
    for (int ks = 0; ks < 2; ++ks) {
      bf16x8_t at = *(const bf16x8_t*)&tl[fr * 72 + ks * 32 + quad * 8];
#pragma unroll
      for (int n = 0; n < 4; n++) {
        bf16x8_t bu = *(const bf16x8_t*)&U0[(size_t)(n * 16 + fr) * 1024 + cb +
                                            ks * 32 + quad * 8];
        uacc[n] = __builtin_amdgcn_mfma_f32_16x16x32_bf16(at, bu, uacc[n], 0, 0, 0);
      }
    }
  }

  // cross-wave reduction of u partials
  {
    float* up = &upart[w * 16 * 68];
#pragma unroll
    for (int n = 0; n < 4; n++)
#pragma unroll
      for (int r = 0; r < 4; r++)
        up[(quad * 4 + r) * 68 + n * 16 + fr] = uacc[n][r];
  }
  __syncthreads();
  {
    int m = tid >> 4;
    int c0 = (tid & 15) * 4;
    f32x4_t s = {0.f, 0.f, 0.f, 0.f};
#pragma unroll
    for (int wv = 0; wv < 4; wv++)
      s += *(const f32x4_t*)&upart[wv * 16 * 68 + m * 68 + c0];
    u16x4_t o = { f2bf(s[0]), f2bf(s[1]), f2bf(s[2]), f2bf(s[3]) };
    *(u16x4_t*)&u_out[(size_t)(rowBase + m) * 64 + c0] = o;
  }
}

// ---------------------------------------------------------------------------
// Fused hyper-GEMM + per-sample contraction (col' = s*64+r permutation),
// PLUS appended cvt blocks (blockIdx.x >= 2048) converting the NEXT layer's
// weights while the GEMM runs.  (Round-0 verified: 80 us/dispatch.)
__global__ __launch_bounds__(256, 2) void k_hyper(
    const unsigned short* __restrict__ A,    // [8192 x 1024] bf16
    const unsigned short* __restrict__ Wmb,  // [4096 x 1024] bf16
    const unsigned short* __restrict__ ug,   // [8192 x 64] bf16
    const float* __restrict__ bm,            // [4096] fp32
    unsigned short* __restrict__ h_out,      // [8192 x 64] bf16
    CvtSeg cs) {
  __shared__ unsigned short smem[16384];

  if (blockIdx.x >= 2048) {                  // appended conversion work
    cvt_block(cs, blockIdx.x - 2048, threadIdx.x);
    return;
  }

  unsigned short* As = smem;
  unsigned short* Bs = smem + 8192;
  const int K = 1024;

  const int tid = threadIdx.x;
  const int lane = tid & 63;
  const int w = tid >> 6;
  const int wrow0 = (w & 1) * 64;
  const int wcol0 = (w >> 1) * 64;
  const int bx = blockIdx.x & 31;
  const int by = blockIdx.x >> 5;
  const int rowBase = by * 128;
  const int colBase = bx * 128;

  const int rl = lane >> 3;
  const int kbg = (lane & 7) ^ rl;
  const int fr = lane & 15;
  const int quad = lane >> 4;

  f32x4_t acc[4][4];
#pragma unroll
  for (int i = 0; i < 4; i++)
#pragma unroll
    for (int j = 0; j < 4; j++) acc[i][j] = f32x4_t{0.f, 0.f, 0.f, 0.f};

  for (int kt = 0; kt < K; kt += 64) {
    __syncthreads();
#pragma unroll
    for (int jj = 0; jj < 4; ++jj) {
      int tr = w * 32 + jj * 8 + rl;
      int ct = colBase + tr;
      int pr = ((ct & 63) << 6) | (ct >> 6);  // Wm row for hyper-col ct
      const unsigned short* ga = A + (size_t)(rowBase + tr) * K + kt + kbg * 8;
      const unsigned short* gb = Wmb + (size_t)pr * K + kt + kbg * 8;
      __builtin_amdgcn_global_load_lds(
          (const __attribute__((address_space(1))) void*)ga,
          (__attribute__((address_space(3))) void*)&As[(w * 32 + jj * 8) * 64],
          16, 0, 0);
      __builtin_amdgcn_global_load_lds(
          (const __attribute__((address_space(1))) void*)gb,
          (__attribute__((address_space(3))) void*)&Bs[(w * 32 + jj * 8) * 64],
          16, 0, 0);
    }
    __syncthreads();

#pragma unroll
    for (int ks = 0; ks < 2; ++ks) {
      bf16x8_t a[4], b[4];
#pragma unroll
      for (int i = 0; i < 4; i++) {
        int m = wrow0 + i * 16 + fr;
        int slot = (ks * 4 + quad) ^ (m & 7);
        a[i] = *(const bf16x8_t*)&As[m * 64 + slot * 8];
      }
#pragma unroll
      for (int j = 0; j < 4; j++) {
        int n = wcol0 + j * 16 + fr;
        int slot = (ks * 4 + quad) ^ (n & 7);
        b[j] = *(const bf16x8_t*)&Bs[n * 64 + slot * 8];
      }
#pragma unroll
      for (int i = 0; i < 4; i++)
#pragma unroll
        for (int j = 0; j < 4; j++)
          acc[i][j] = __builtin_amdgcn_mfma_f32_16x16x32_bf16(a[i], b[j],
                                                              acc[i][j], 0, 0, 0);
    }
  }

  // ---- fused contraction epilogue ----
  __syncthreads();

  // stage u transposed: u_t[r][row], stride 136 to spread banks
  {
    int row = tid >> 1;
    int c0 = (tid & 1) * 32;
    const unsigned short* up = ug + (size_t)(rowBase + row) * 64 + c0;
    bf16x8_t v0 = *(const bf16x8_t*)(up);
    bf16x8_t v1 = *(const bf16x8_t*)(up + 8);
    bf16x8_t v2 = *(const bf16x8_t*)(up + 16);
    bf16x8_t v3 = *(const bf16x8_t*)(up + 24);
#pragma unroll
    for (int m = 0; m < 8; m++) {
      smem[(c0 + m) * 136 + row] = (unsigned short)v0[m];
      smem[(c0 + 8 + m) * 136 + row] = (unsigned short)v1[m];
      smem[(c0 + 16 + m) * 136 + row] = (unsigned short)v2[m];
      smem[(c0 + 24 + m) * 136 + row] = (unsigned short)v3[m];
    }
  }
  __syncthreads();

  const int s = bx * 2 + (w >> 1);
  float bmv[4];
#pragma unroll
  for (int j = 0; j < 4; j++) bmv[j] = bm[(j * 16 + fr) * 64 + s];

#pragma unroll
  for (int i = 0; i < 4; i++) {
    int row0 = wrow0 + i * 16 + quad * 4;
    bf16x4_t uv[4];
#pragma unroll
    for (int j = 0; j < 4; j++)
      uv[j] = *(const bf16x4_t*)&smem[(j * 16 + fr) * 136 + row0];
#pragma unroll
    for (int r = 0; r < 4; r++) {
      float p = 0.f;
#pragma unroll
      for (int j = 0; j < 4; j++)
        p += bf2f((unsigned short)uv[j][r]) * (acc[i][j][r] + bmv[j]);
      p += __shfl_xor(p, 1, 64);
      p += __shfl_xor(p, 2, 64);
      p += __shfl_xor(p, 4, 64);
      p += __shfl_xor(p, 8, 64);
      if (fr == 0)
        h_out[(size_t)(rowBase + row0 + r) * 64 + s] = f2bf(p);
    }
  }
}

// ---------------------------------------------------------------------------
// Fused V-GEMM + next-layer u-GEMM (r4-proven).
__global__ __launch_bounds__(256, 2) void vu_fused(
    const unsigned short* __restrict__ h,    // [8192 x 64] bf16
    const unsigned short* __restrict__ Vb,   // [1024 x 64] bf16
    const float* __restrict__ bias,          // [1024] fp32
    const unsigned short* __restrict__ Un,   // [64 x 1024] bf16 (next U)
    unsigned short* __restrict__ act,        // [8192 x 1024] bf16
    unsigned short* __restrict__ u_out) {    // [8192 x 64] bf16
  __shared__ unsigned short tlds[4 * 16 * 72];
  __shared__ float upart[4 * 16 * 68];

  const int tid = threadIdx.x;
  const int lane = tid & 63;
  const int w = tid >> 6;
  const int fr = lane & 15;
  const int quad = lane >> 4;
  const int rowBase = blockIdx.x * 16;

  unsigned short* tl = &tlds[w * 16 * 72];

  bf16x8_t ah0 = *(const bf16x8_t*)&h[(size_t)(rowBase + fr) * 64 + quad * 8];
  bf16x8_t ah1 = *(const bf16x8_t*)&h[(size_t)(rowBase + fr) * 64 + 32 + quad * 8];

  f32x4_t uacc[4];
#pragma unroll
  for (int n = 0; n < 4; n++) uacc[n] = f32x4_t{0.f, 0.f, 0.f, 0.f};

  for (int it = 0; it < 4; ++it) {
    const int cb = w * 256 + it * 64;

    f32x4_t tacc[4];
#pragma unroll
    for (int nt = 0; nt < 4; nt++) {
      const unsigned short* vrow = Vb + (size_t)(cb + nt * 16 + fr) * 64;
      bf16x8_t b0 = *(const bf16x8_t*)&vrow[quad * 8];
      bf16x8_t b1 = *(const bf16x8_t*)&vrow[32 + quad * 8];
      f32x4_t z = {0.f, 0.f, 0.f, 0.f};
      z = __builtin_amdgcn_mfma_f32_16x16x32_bf16(ah0, b0, z, 0, 0, 0);
      tacc[nt] = __builtin_amdgcn_mfma_f32_16x16x32_bf16(ah1, b1, z, 0, 0, 0);
    }

#pragma unroll
    for (int nt = 0; nt < 4; nt++) {
      float bv = bias[cb + nt * 16 + fr];
#pragma unroll
      for (int r = 0; r < 4; r++) {
        float v = tacc[nt][r] + bv;
        v = v > 0.f ? v : 0.f;
        tl[(quad * 4 + r) * 72 + nt * 16 + fr] = f2bf(v);
      }
    }

    {
      int m2 = lane >> 2;
      int kc = (lane & 3) * 16;
      bf16x8_t t0 = *(const bf16x8_t*)&tl[m2 * 72 + kc];
      bf16x8_t t1 = *(const bf16x8_t*)&tl[m2 * 72 + kc + 8];
      unsigned short* ap = act + (size_t)(rowBase + m2) * 1024 + cb + kc;
      *(bf16x8_t*)ap = t0;
      *(bf16x8_t*)(ap + 8) = t1;
    }

#pragma unroll
    for (int ks = 0; ks < 2; ++ks) {
      bf16x8_t at = *(const bf16x8_t*)&tl[fr * 72 + ks * 32 + quad * 8];
#pragma unroll
      for (int n = 0; n < 4; n++) {
        bf16x8_t bu = *(const bf16x8_t*)&Un[(size_t)(n * 16 + fr) * 1024 + cb +
                                            ks * 32 + quad * 8];
        uacc[n] = __builtin_amdgcn_mfma_f32_16x16x32_bf16(at, bu, uacc[n], 0, 0, 0);
      }
    }
  }

  {
    float* up = &upart[w * 16 * 68];
#pragma unroll
    for (int n = 0; n < 4; n++)
#pragma unroll
      for (int r = 0; r < 4; r++)
        up[(quad * 4 + r) * 68 + n * 16 + fr] = uacc[n][r];
  }
  __syncthreads();
  {
    int m = tid >> 4;
    int c0 = (tid & 15) * 4;
    f32x4_t s = {0.f, 0.f, 0.f, 0.f};
#pragma unroll
    for (int wv = 0; wv < 4; wv++)
      s += *(const f32x4_t*)&upart[wv * 16 * 68 + m * 68 + c0];
    u16x4_t o = { f2bf(s[0]), f2bf(s[1]), f2bf(s[2]), f2bf(s[3]) };
    *(u16x4_t*)&u_out[(size_t)(rowBase + m) * 64 + c0] = o;
  }
}

// ---------------------------------------------------------------------------
// Final layer: out = h @ V^T + b (fp32), K = 64.
// Epilogue: LDS-transposed panel stores -> fully coalesced float4 writes
// (the 32 MB fp32 output is the largest HBM write in the pipeline; the raw
// MFMA C-layout only allows 64B-granular scalar stores).
__global__ __launch_bounds__(256, 2) void k_final(
    const unsigned short* __restrict__ A, const unsigned short* __restrict__ B,
    const float* __restrict__ bias, float* __restrict__ Cout) {
  __shared__ union {
    unsigned short ab[2][128 * 64];   // staging for A,B during MFMA phase
    float pan[2][128 * 33];           // two 128x32 output panels (+1 pad)
  } sm;
  unsigned short* As = sm.ab[0];
  unsigned short* Bs = sm.ab[1];

  const int tid = threadIdx.x;
  const int lane = tid & 63;
  const int w = tid >> 6;
  const int wrow0 = (w & 1) * 64;
  const int wcol0 = (w >> 1) * 64;
  const int rowBase = blockIdx.y * 128;
  const int colBase = blockIdx.x * 128;

  const int rl = lane >> 3;
  const int kbg = (lane & 7) ^ rl;
  const int fr = lane & 15;
  const int quad = lane >> 4;

  f32x4_t acc[4][4];
#pragma unroll
  for (int i = 0; i < 4; i++)
#pragma unroll
    for (int j = 0; j < 4; j++) acc[i][j] = f32x4_t{0.f, 0.f, 0.f, 0.f};

#pragma unroll
  for (int jj = 0; jj < 4; ++jj) {
    int tr = w * 32 + jj * 8 + rl;
    const unsigned short* ga = A + (size_t)(rowBase + tr) * 64 + kbg * 8;
    const unsigned short* gb = B + (size_t)(colBase + tr) * 64 + kbg * 8;
    __builtin_amdgcn_global_load_lds(
        (const __attribute__((address_space(1))) void*)ga,
        (__attribute__((address_space(3))) void*)&As[(w * 32 + jj * 8) * 64],
        16, 0, 0);
    __builtin_amdgcn_global_load_lds(
        (const __attribute__((address_space(1))) void*)gb,
        (__attribute__((address_space(3))) void*)&Bs[(w * 32 + jj * 8) * 64],
        16, 0, 0);
  }
  __syncthreads();

#pragma unroll
  for (int ks = 0; ks < 2; ++ks) {
    bf16x8_t a[4], b[4];
#pragma unroll
    for (int i = 0; i < 4; i++) {
      int m = wrow0 + i * 16 + fr;
      int slot = (ks * 4 + quad) ^ (m & 7);
      a[i] = *(const bf16x8_t*)&As[m * 64 + slot * 8];
    }
#pragma unroll
    for (int j = 0; j < 4; j++) {
      int n = wcol0 + j * 16 + fr;
      int slot = (ks * 4 + quad) ^ (n & 7);
      b[j] = *(const bf16x8_t*)&Bs[n * 64 + slot * 8];
    }
#pragma unroll
    for (int i = 0; i < 4; i++)
#pragma unroll
      for (int j = 0; j < 4; j++)
        acc[i][j] = __builtin_amdgcn_mfma_f32_16x16x32_bf16(a[i], b[j],
                                                            acc[i][j], 0, 0, 0);
  }

  // bias per output column this thread owns (j fragment index)
  float bv[4];
#pragma unroll
  for (int j = 0; j < 4; j++) bv[j] = bias[colBase + wcol0 + j * 16 + fr];

  // Two rounds; per round, wave-pair {w0,w1} fills pan[0] (col-half 0) and
  // {w2,w3} fills pan[1] (col-half 1), 32 cols each; then all 256 threads
  // stream both panels out as contiguous float4 runs.
#pragma unroll
  for (int rp = 0; rp < 2; ++rp) {
    __syncthreads();   // previous use of the LDS region complete
    {
      float* P = sm.pan[w >> 1];
#pragma unroll
      for (int jj = 0; jj < 2; ++jj) {
        int j = rp * 2 + jj;
        int colp = jj * 16 + fr;            // 0..31 within panel
#pragma unroll
        for (int i = 0; i < 4; i++)
#pragma unroll
          for (int r = 0; r < 4; r++) {
            int row = wrow0 + i * 16 + quad * 4 + r;
            P[row * 33 + colp] = acc[i][j][r] + bv[j];
          }
      }
    }
    __syncthreads();
    {
      int row = tid >> 1;
      int ch = (tid & 1) * 16;              // 16-float half of the 32-col panel
#pragma unroll
      for (int pb = 0; pb < 2; ++pb) {
        const float* Pr = &sm.pan[pb][row * 33 + ch];
        float4 v0 = { Pr[0],  Pr[1],  Pr[2],  Pr[3]  };
        float4 v1 = { Pr[4],  Pr[5],  Pr[6],  Pr[7]  };
        float4 v2 = { Pr[8],  Pr[9],  Pr[10], Pr[11] };
        float4 v3 = { Pr[12], Pr[13], Pr[14], Pr[15] };
        float* out = &Cout[(size_t)(rowBase + row) * 1024 + colBase + pb * 64 +
                           rp * 32 + ch];
        ((float4*)out)[0] = v0;
        ((float4*)out)[1] = v1;
        ((float4*)out)[2] = v2;
        ((float4*)out)[3] = v3;
      }
    }
  }
}

// ---------------------------------------------------------------------------
extern "C" void kernel_launch(void* const* d_in, const int* in_sizes, int n_in,
                              void* d_out, int out_size, void* d_ws,
                              size_t ws_size, hipStream_t stream) {
  const float* x = (const float*)d_in[0];
  const float* Wm[3] = {(const float*)d_in[1], (const float*)d_in[6], (const float*)d_in[11]};
  const float* bm[3] = {(const float*)d_in[2], (const float*)d_in[7], (const float*)d_in[12]};
  const float* U[3]  = {(const float*)d_in[3], (const float*)d_in[8], (const float*)d_in[13]};
  const float* V[3]  = {(const float*)d_in[4], (const float*)d_in[9], (const float*)d_in[14]};
  const float* bs[3] = {(const float*)d_in[5], (const float*)d_in[10], (const float*)d_in[15]};

  char* p = (char*)d_ws;
  unsigned short* xb = (unsigned short*)p;  p += 8192UL * 1024 * 2;
  unsigned short* act = (unsigned short*)p; p += 8192UL * 1024 * 2;
  unsigned short* Wmb[3];
  for (int l = 0; l < 3; l++) { Wmb[l] = (unsigned short*)p; p += 4096UL * 1024 * 2; }
  unsigned short* Ub[3];
  for (int l = 0; l < 3; l++) { Ub[l] = (unsigned short*)p; p += 64UL * 1024 * 2; }
  unsigned short* Vb[3];
  for (int l = 0; l < 3; l++) { Vb[l] = (unsigned short*)p; p += 1024UL * 64 * 2; }
  unsigned short* hb = (unsigned short*)p;  p += 8192UL * 64 * 2;
  unsigned short* ug = (unsigned short*)p;  p += 8192UL * 64 * 2;

  // Dispatch 1: convert Wm0 + U0 (38 MB read) — the only serial conversions
  CvtSeg c0;
  c0.src[0] = Wm[0]; c0.dst[0] = Wmb[0];
  c0.src[1] = U[0];  c0.dst[1] = Ub[0];
  c0.src[2] = U[0];  c0.dst[2] = Ub[0];   // unused (bstart collapse)
  c0.bstart[0] = 0; c0.bstart[1] = 4096; c0.bstart[2] = 4160; c0.bstart[3] = 4160;
  k_cvt<<<4160, 256, 0, stream>>>(c0);

  // Dispatch 2: x cvt + u0 = x @ U0^T, fused (writes xb and ug)
  xu_fused<<<512, 256, 0, stream>>>(x, Ub[0], xb, ug);

  // cvt tables for the work appended to each hyper dispatch
  CvtSeg ch[3];
  ch[0].src[0] = Wm[1]; ch[0].dst[0] = Wmb[1];
  ch[0].src[1] = U[1];  ch[0].dst[1] = Ub[1];
  ch[0].src[2] = V[0];  ch[0].dst[2] = Vb[0];
  ch[0].bstart[0] = 0; ch[0].bstart[1] = 4096; ch[0].bstart[2] = 4160; ch[0].bstart[3] = 4224;
  ch[1].src[0] = Wm[2]; ch[1].dst[0] = Wmb[2];
  ch[1].src[1] = U[2];  ch[1].dst[1] = Ub[2];
  ch[1].src[2] = V[1];  ch[1].dst[2] = Vb[1];
  ch[1].bstart[0] = 0; ch[1].bstart[1] = 4096; ch[1].bstart[2] = 4160; ch[1].bstart[3] = 4224;
  ch[2].src[0] = V[2]; ch[2].dst[0] = Vb[2];
  ch[2].src[1] = V[2]; ch[2].dst[1] = Vb[2];   // unused
  ch[2].src[2] = V[2]; ch[2].dst[2] = Vb[2];   // unused
  ch[2].bstart[0] = 0; ch[2].bstart[1] = 64; ch[2].bstart[2] = 64; ch[2].bstart[3] = 64;

  const int hyperGrid[3] = {2048 + 4224, 2048 + 4224, 2048 + 64};

  const unsigned short* cur = xb;
  for (int l = 0; l < 3; l++) {
    // fused: h = einsum('br,brs->bs', u, cur@Wm^T + bm)  [+ appended cvt]
    k_hyper<<<hyperGrid[l], 256, 0, stream>>>(cur, Wmb[l], ug, bm[l], hb, ch[l]);
    if (l < 2) {
      // act = relu(h@V^T + b); u(next) = act @ U[l+1]^T
      vu_fused<<<512, 256, 0, stream>>>(hb, Vb[l], bs[l], Ub[l + 1], act, ug);
      cur = act;
    } else {
      k_final<<<dim3(8, 64), 256, 0, stream>>>(hb, Vb[2], bs[2], (float*)d_out);
    }
  }
}

// Round 6
// 417.831 us; speedup vs baseline: 1.0375x; 1.0268x over previous
//
#include <hip/hip_runtime.h>
#include <stdint.h>

typedef short bf16x8_t __attribute__((ext_vector_type(8)));
typedef short bf16x4_t __attribute__((ext_vector_type(4)));
typedef float f32x4_t __attribute__((ext_vector_type(4)));
typedef unsigned short u16x4_t __attribute__((ext_vector_type(4)));
typedef unsigned short u16x8_t __attribute__((ext_vector_type(8)));

#define DEV static __device__ __forceinline__

DEV float bf2f(unsigned short u) {
  union { unsigned int i; float f; } v; v.i = ((unsigned int)u) << 16; return v.f;
}
DEV unsigned short f2bf(float f) {
  union { float f; unsigned int i; } v; v.f = f;
  unsigned int x = v.i;
  unsigned int lsb = (x >> 16) & 1u;
  x += 0x7fffu + lsb;
  return (unsigned short)(x >> 16);
}

// Up to 3 cvt segments; boundaries in blocks (block-uniform).
struct CvtSeg {
  const float* src[3];
  unsigned short* dst[3];
  int bstart[4];   // bstart[0]=0; bstart[3]=total blocks
};

DEV void cvt_block(const CvtSeg& cs, int vb, int tid) {   // 256-thread variant
  int seg = (vb >= cs.bstart[1] ? 1 : 0) + (vb >= cs.bstart[2] ? 1 : 0);
  int local = (vb - cs.bstart[seg]) * 256 + tid;
  float4 v = ((const float4*)cs.src[seg])[local];
  u16x4_t o = { f2bf(v.x), f2bf(v.y), f2bf(v.z), f2bf(v.w) };
  *(u16x4_t*)&cs.dst[seg][local * 4] = o;
}

DEV void cvt_block512(const CvtSeg& cs, int vb, int tid) { // 512-thread variant
  int seg = (vb >= cs.bstart[1] ? 1 : 0) + (vb >= cs.bstart[2] ? 1 : 0);
  int local = (vb - cs.bstart[seg]) * 512 + tid;
  float4 v = ((const float4*)cs.src[seg])[local];
  u16x4_t o = { f2bf(v.x), f2bf(v.y), f2bf(v.z), f2bf(v.w) };
  *(u16x4_t*)&cs.dst[seg][local * 4] = o;
}

// ---------------------------------------------------------------------------
// Dispatch 1: convert Wm0 + U0 only (critical path for xu_fused / hyper-0)
__global__ __launch_bounds__(256) void k_cvt(CvtSeg cs) {
  cvt_block(cs, blockIdx.x, threadIdx.x);
}

// ---------------------------------------------------------------------------
// xu_fused: converts x (fp32 -> bf16 in xb) AND computes u0 = x @ U0^T.
__global__ __launch_bounds__(256, 2) void xu_fused(
    const float* __restrict__ x,            // [8192 x 1024] fp32
    const unsigned short* __restrict__ U0,  // [64 x 1024] bf16
    unsigned short* __restrict__ xb,        // [8192 x 1024] bf16 out
    unsigned short* __restrict__ u_out) {   // [8192 x 64] bf16 out
  __shared__ unsigned short tlds[4 * 16 * 72];  // per-wave x chunk [16][72]
  __shared__ float upart[4 * 16 * 68];          // per-wave u partial [16][68]

  const int tid = threadIdx.x;
  const int lane = tid & 63;
  const int w = tid >> 6;
  const int fr = lane & 15;
  const int quad = lane >> 4;
  const int rowBase = blockIdx.x * 16;

  unsigned short* tl = &tlds[w * 16 * 72];
  const int m2 = lane >> 2;          // row within the 16-row block
  const int kc = (lane & 3) * 16;    // 16-col sub-chunk

  f32x4_t uacc[4];
#pragma unroll
  for (int n = 0; n < 4; n++) uacc[n] = f32x4_t{0.f, 0.f, 0.f, 0.f};

  for (int it = 0; it < 4; ++it) {
    const int cb = w * 256 + it * 64;  // k-chunk base

    {
      const float* xp = x + (size_t)(rowBase + m2) * 1024 + cb + kc;
      float4 v0 = *(const float4*)(xp);
      float4 v1 = *(const float4*)(xp + 4);
      float4 v2 = *(const float4*)(xp + 8);
      float4 v3 = *(const float4*)(xp + 12);
      u16x8_t o0 = { f2bf(v0.x), f2bf(v0.y), f2bf(v0.z), f2bf(v0.w),
                     f2bf(v1.x), f2bf(v1.y), f2bf(v1.z), f2bf(v1.w) };
      u16x8_t o1 = { f2bf(v2.x), f2bf(v2.y), f2bf(v2.z), f2bf(v2.w),
                     f2bf(v3.x), f2bf(v3.y), f2bf(v3.z), f2bf(v3.w) };
      *(u16x8_t*)&tl[m2 * 72 + kc] = o0;
      *(u16x8_t*)&tl[m2 * 72 + kc + 8] = o1;
      unsigned short* xo = xb + (size_t)(rowBase + m2) * 1024 + cb + kc;
      *(u16x8_t*)xo = o0;
      *(u16x8_t*)(xo + 8) = o1;
    }

#pragma unroll
    for (int ks = 0; ks < 2; ++ks) {
      bf16x8_t at = *(const bf16x8_t*)&tl[fr * 72 + ks * 32 + quad * 8];
#pragma unroll
      for (int n = 0; n < 4; n++) {
        bf16x8_t bu = *(const bf16x8_t*)&U0[(size_t)(n * 16 + fr) * 1024 + cb +
                                            ks * 32 + quad * 8];
        uacc[n] = __builtin_amdgcn_mfma_f32_16x16x32_bf16(at, bu, uacc[n], 0, 0, 0);
      }
    }
  }

  {
    float* up = &upart[w * 16 * 68];
#pragma unroll
    for (int n = 0; n < 4; n++)
#pragma unroll
      for (int r = 0; r < 4; r++)
        up[(quad * 4 + r) * 68 + n * 16 + fr] = uacc[n][r];
  }
  __syncthreads();
  {
    int m = tid >> 4;
    int c0 = (tid & 15) * 4;
    f32x4_t s = {0.f, 0.f, 0.f, 0.f};
#pragma unroll
    for (int wv = 0; wv < 4; wv++)
      s += *(const f32x4_t*)&upart[wv * 16 * 68 + m * 68 + c0];
    u16x4_t o = { f2bf(s[0]), f2bf(s[1]), f2bf(s[2]), f2bf(s[3]) };
    *(u16x4_t*)&u_out[(size_t)(rowBase + m) * 64 + c0] = o;
  }
}

// ---------------------------------------------------------------------------
// Fused hyper-GEMM + per-sample contraction, 256x256 tile, BK=64, 8 waves.
// m201-faithful 4-phase/K-tile schedule (== template's 8 phases / 2 K-tiles):
//   P1: read a_m0(8)+b_n0(4); stage A0(t+1); bar; lgkm0; 16 MFMA m0n0; vmcnt(4); bar
//   P2: read b_n1(4);         stage B0(t+1); bar; lgkm0; 16 MFMA m0n1; vmcnt(4); bar
//   P3: read a_m1(8);         stage B1(t+1); bar; lgkm0; 16 MFMA m1n1;           bar
//   P4: read b_n0(4, reload); stage A1(t+1); bar; lgkm0; 16 MFMA m1n0; vmcnt(4); bar
// Counted vmcnt: half-tiles staged >=3 phases before consumption; 4-8 loads
// always in flight (never drains until the tail).
// LDS [2 dbuf][2 qhalf][128][64] shorts per operand; qhalf groups rows by the
// quadrant that consumes them (A-q0 = rows {0-63,128-191}; B-q0 = cols
// {0-31,64-95,128-159,192-223}). 128B rows + XOR-8 slot swizzle (verified
// conflict-free, 262K, r2/r3).
// Appended cvt blocks (blockIdx.x >= 512) convert the NEXT layer's weights.
#define GLD(gp, lp)                                              \
  __builtin_amdgcn_global_load_lds(                              \
      (const __attribute__((address_space(1))) void*)(gp),       \
      (__attribute__((address_space(3))) void*)(lp), 16, 0, 0)

__global__ __launch_bounds__(512, 1) void k_hyper(
    const unsigned short* __restrict__ A,    // [8192 x 1024] bf16
    const unsigned short* __restrict__ Wmb,  // [4096 x 1024] bf16
    const unsigned short* __restrict__ ug,   // [8192 x 64] bf16
    const float* __restrict__ bm,            // [4096] fp32
    unsigned short* __restrict__ h_out,      // [8192 x 64] bf16
    CvtSeg cs) {
  __shared__ unsigned short lds[65536];      // 128 KiB

  if (blockIdx.x >= 512) {                   // appended conversion work
    cvt_block512(cs, blockIdx.x - 512, threadIdx.x);
    return;
  }

  unsigned short* As = lds;                  // [2][2][128][64]
  unsigned short* Bs = lds + 32768;

  const int tid = threadIdx.x;
  const int lane = tid & 63;
  const int w = tid >> 6;        // wave 0..7
  const int wr = w >> 2;         // 0..1  M-half
  const int wc = w & 3;          // 0..3  N-quarter
  const int bx = blockIdx.x & 15;
  const int by = blockIdx.x >> 4;
  const int rowBase = by * 256;
  const int colBase = bx * 256;
  const int fr = lane & 15;
  const int quad = lane >> 4;

  // --- staging addresses ---
  const int rl8 = lane >> 3;             // row 0..7 within 8-row wave group
  const int kbg = (lane & 7) ^ rl8;      // inverse-swizzled source chunk
  const int wb = w * 8 + rl8;            // base local row 0..63

  // A: one base pointer; (q,p) row offsets {0,128,64,192}
  const unsigned short* gAbase =
      A + (size_t)(rowBase + wb) * 1024 + kbg * 8;

  // B: 4 named pointers (q,p) with the hyper-col permutation folded in
  const int wb5 = wb >> 5;               // 0..1
  const int wb31 = wb & 31;
  int ctl00 = (0 * 2 + wb5) * 64 + 0 * 32 + wb31;   // q0 p0
  int ctl01 = (1 * 2 + wb5) * 64 + 0 * 32 + wb31;   // q0 p1
  int ctl10 = (0 * 2 + wb5) * 64 + 1 * 32 + wb31;   // q1 p0
  int ctl11 = (1 * 2 + wb5) * 64 + 1 * 32 + wb31;   // q1 p1
  int ct;
  ct = colBase + ctl00;
  const unsigned short* gB00 =
      Wmb + (size_t)(((ct & 63) << 6) | (ct >> 6)) * 1024 + kbg * 8;
  ct = colBase + ctl01;
  const unsigned short* gB01 =
      Wmb + (size_t)(((ct & 63) << 6) | (ct >> 6)) * 1024 + kbg * 8;
  ct = colBase + ctl10;
  const unsigned short* gB10 =
      Wmb + (size_t)(((ct & 63) << 6) | (ct >> 6)) * 1024 + kbg * 8;
  ct = colBase + ctl11;
  const unsigned short* gB11 =
      Wmb + (size_t)(((ct & 63) << 6) | (ct >> 6)) * 1024 + kbg * 8;

  const int ldw = (w * 8) * 64;          // wave's LDS row-block offset (shorts)

#define STAGE_A0(tt) do { const int l_ = (((tt)&1)*16384) + 0*8192 + ldw;   \
    GLD(gAbase + (size_t)0 * 1024 + (tt) * 64, &As[l_]);                    \
    GLD(gAbase + (size_t)128 * 1024 + (tt) * 64, &As[l_ + 4096]); } while (0)
#define STAGE_A1(tt) do { const int l_ = (((tt)&1)*16384) + 1*8192 + ldw;   \
    GLD(gAbase + (size_t)64 * 1024 + (tt) * 64, &As[l_]);                   \
    GLD(gAbase + (size_t)192 * 1024 + (tt) * 64, &As[l_ + 4096]); } while (0)
#define STAGE_B0(tt) do { const int l_ = (((tt)&1)*16384) + 0*8192 + ldw;   \
    GLD(gB00 + (tt) * 64, &Bs[l_]);                                         \
    GLD(gB01 + (tt) * 64, &Bs[l_ + 4096]); } while (0)
#define STAGE_B1(tt) do { const int l_ = (((tt)&1)*16384) + 1*8192 + ldw;   \
    GLD(gB10 + (tt) * 64, &Bs[l_]);                                         \
    GLD(gB11 + (tt) * 64, &Bs[l_ + 4096]); } while (0)

  // --- swizzled ds_read bases (shorts) ---
  const int slot0 = ((0 + quad) ^ (fr & 7)) * 8;   // ks=0
  const int slot1 = ((4 + quad) ^ (fr & 7)) * 8;   // ks=1
  const int aRow = (wr * 64 + fr) * 64;            // + i'*1024 within qhalf
  const int bRow = (wc * 32 + fr) * 64;            // + j'*1024 within qhalf

  f32x4_t acc[8][4];
#pragma unroll
  for (int i = 0; i < 8; i++)
#pragma unroll
    for (int j = 0; j < 4; j++) acc[i][j] = f32x4_t{0.f, 0.f, 0.f, 0.f};

  // prologue: tile0's 4 half-tiles in order A0,B0,B1,A1; wait oldest 2 units
  STAGE_A0(0); STAGE_B0(0); STAGE_B1(0); STAGE_A1(0);
  asm volatile("s_waitcnt vmcnt(4)" ::: "memory");
  __builtin_amdgcn_s_barrier();

#pragma unroll 2
  for (int t = 0; t < 16; ++t) {
    const int d = (t & 1) * 16384;
    bf16x8_t am[4][2], bn[2][2], bn1[2][2];
    // ---------------- P1: m0 x n0 ----------------
#pragma unroll
    for (int i = 0; i < 4; i++) {
      am[i][0] = *(const bf16x8_t*)&As[d + aRow + i * 1024 + slot0];
      am[i][1] = *(const bf16x8_t*)&As[d + aRow + i * 1024 + slot1];
    }
#pragma unroll
    for (int j = 0; j < 2; j++) {
      bn[j][0] = *(const bf16x8_t*)&Bs[d + bRow + j * 1024 + slot0];
      bn[j][1] = *(const bf16x8_t*)&Bs[d + bRow + j * 1024 + slot1];
    }
    if (t < 15) STAGE_A0(t + 1);
    __builtin_amdgcn_s_barrier();
    asm volatile("s_waitcnt lgkmcnt(0)" ::: "memory");
    __builtin_amdgcn_sched_barrier(0);
    __builtin_amdgcn_s_setprio(1);
#pragma unroll
    for (int i = 0; i < 4; i++)
#pragma unroll
      for (int j = 0; j < 2; j++) {
        acc[i][j] = __builtin_amdgcn_mfma_f32_16x16x32_bf16(am[i][0], bn[j][0],
                                                            acc[i][j], 0, 0, 0);
        acc[i][j] = __builtin_amdgcn_mfma_f32_16x16x32_bf16(am[i][1], bn[j][1],
                                                            acc[i][j], 0, 0, 0);
      }
    __builtin_amdgcn_s_setprio(0);
    if (t < 15) { asm volatile("s_waitcnt vmcnt(4)" ::: "memory"); }
    else        { asm volatile("s_waitcnt vmcnt(2)" ::: "memory"); }
    __builtin_amdgcn_s_barrier();
    // ---------------- P2: m0 x n1 ----------------
#pragma unroll
    for (int j = 0; j < 2; j++) {
      bn1[j][0] = *(const bf16x8_t*)&Bs[d + 8192 + bRow + j * 1024 + slot0];
      bn1[j][1] = *(const bf16x8_t*)&Bs[d + 8192 + bRow + j * 1024 + slot1];
    }
    if (t < 15) STAGE_B0(t + 1);
    __builtin_amdgcn_s_barrier();
    asm volatile("s_waitcnt lgkmcnt(0)" ::: "memory");
    __builtin_amdgcn_sched_barrier(0);
    __builtin_amdgcn_s_setprio(1);
#pragma unroll
    for (int i = 0; i < 4; i++)
#pragma unroll
      for (int j = 0; j < 2; j++) {
        acc[i][2 + j] = __builtin_amdgcn_mfma_f32_16x16x32_bf16(
            am[i][0], bn1[j][0], acc[i][2 + j], 0, 0, 0);
        acc[i][2 + j] = __builtin_amdgcn_mfma_f32_16x16x32_bf16(
            am[i][1], bn1[j][1], acc[i][2 + j], 0, 0, 0);
      }
    __builtin_amdgcn_s_setprio(0);
    if (t < 15) { asm volatile("s_waitcnt vmcnt(4)" ::: "memory"); }
    else        { asm volatile("s_waitcnt vmcnt(0)" ::: "memory"); }
    __builtin_amdgcn_s_barrier();
    // ---------------- P3: m1 x n1 ----------------
#pragma unroll
    for (int i = 0; i < 4; i++) {
      am[i][0] = *(const bf16x8_t*)&As[d + 8192 + aRow + i * 1024 + slot0];
      am[i][1] = *(const bf16x8_t*)&As[d + 8192 + aRow + i * 1024 + slot1];
    }
    if (t < 15) STAGE_B1(t + 1);
    __builtin_amdgcn_s_barrier();
    asm volatile("s_waitcnt lgkmcnt(0)" ::: "memory");
    __builtin_amdgcn_sched_barrier(0);
    __builtin_amdgcn_s_setprio(1);
#pragma unroll
    for (int i = 0; i < 4; i++)
#pragma unroll
      for (int j = 0; j < 2; j++) {
        acc[4 + i][2 + j] = __builtin_amdgcn_mfma_f32_16x16x32_bf16(
            am[i][0], bn1[j][0], acc[4 + i][2 + j], 0, 0, 0);
        acc[4 + i][2 + j] = __builtin_amdgcn_mfma_f32_16x16x32_bf16(
            am[i][1], bn1[j][1], acc[4 + i][2 + j], 0, 0, 0);
      }
    __builtin_amdgcn_s_setprio(0);
    __builtin_amdgcn_s_barrier();
    // ---------------- P4: m1 x n0 (b_n0 reload) ----------------
#pragma unroll
    for (int j = 0; j < 2; j++) {
      bn[j][0] = *(const bf16x8_t*)&Bs[d + bRow + j * 1024 + slot0];
      bn[j][1] = *(const bf16x8_t*)&Bs[d + bRow + j * 1024 + slot1];
    }
    if (t < 15) STAGE_A1(t + 1);
    __builtin_amdgcn_s_barrier();
    asm volatile("s_waitcnt lgkmcnt(0)" ::: "memory");
    __builtin_amdgcn_sched_barrier(0);
    __builtin_amdgcn_s_setprio(1);
#pragma unroll
    for (int i = 0; i < 4; i++)
#pragma unroll
      for (int j = 0; j < 2; j++) {
        acc[4 + i][j] = __builtin_amdgcn_mfma_f32_16x16x32_bf16(
            am[i][0], bn[j][0], acc[4 + i][j], 0, 0, 0);
        acc[4 + i][j] = __builtin_amdgcn_mfma_f32_16x16x32_bf16(
            am[i][1], bn[j][1], acc[4 + i][j], 0, 0, 0);
      }
    __builtin_amdgcn_s_setprio(0);
    if (t < 15) { asm volatile("s_waitcnt vmcnt(4)" ::: "memory"); }
    __builtin_amdgcn_s_barrier();
  }

  // ---- fused contraction epilogue (verified rounds 1-4) ----
  __syncthreads();

  // stage u transposed: u_t[r 0..63][row 0..255], stride 264 to spread banks
  {
    int row = tid >> 1;
    int c0 = (tid & 1) * 32;
    const unsigned short* up = ug + (size_t)(rowBase + row) * 64 + c0;
    bf16x8_t v0 = *(const bf16x8_t*)(up);
    bf16x8_t v1 = *(const bf16x8_t*)(up + 8);
    bf16x8_t v2 = *(const bf16x8_t*)(up + 16);
    bf16x8_t v3 = *(const bf16x8_t*)(up + 24);
#pragma unroll
    for (int m = 0; m < 8; m++) {
      lds[(c0 + m) * 264 + row] = (unsigned short)v0[m];
      lds[(c0 + 8 + m) * 264 + row] = (unsigned short)v1[m];
      lds[(c0 + 16 + m) * 264 + row] = (unsigned short)v2[m];
      lds[(c0 + 24 + m) * 264 + row] = (unsigned short)v3[m];
    }
  }
  __syncthreads();

  const int s = bx * 4 + wc;
  float bmv[4];
#pragma unroll
  for (int j = 0; j < 4; j++) bmv[j] = bm[(j * 16 + fr) * 64 + s];

#pragma unroll
  for (int i = 0; i < 8; i++) {
    int row0 = wr * 128 + i * 16 + quad * 4;
    bf16x4_t uv[4];
#pragma unroll
    for (int j = 0; j < 4; j++)
      uv[j] = *(const bf16x4_t*)&lds[(j * 16 + fr) * 264 + row0];
#pragma unroll
    for (int r = 0; r < 4; r++) {
      float p = 0.f;
#pragma unroll
      for (int j = 0; j < 4; j++)
        p += bf2f((unsigned short)uv[j][r]) * (acc[i][j][r] + bmv[j]);
      p += __shfl_xor(p, 1, 64);
      p += __shfl_xor(p, 2, 64);
      p += __shfl_xor(p, 4, 64);
      p += __shfl_xor(p, 8, 64);
      if (fr == 0)
        h_out[(size_t)(rowBase + row0 + r) * 64 + s] = f2bf(p);
    }
  }
}

// ---------------------------------------------------------------------------
// Fused V-GEMM + next-layer u-GEMM (r4-proven).
__global__ __launch_bounds__(256, 2) void vu_fused(
    const unsigned short* __restrict__ h,    // [8192 x 64] bf16
    const unsigned short* __restrict__ Vb,   // [1024 x 64] bf16
    const float* __restrict__ bias,          // [1024] fp32
    const unsigned short* __restrict__ Un,   // [64 x 1024] bf16 (next U)
    unsigned short* __restrict__ act,        // [8192 x 1024] bf16
    unsigned short* __restrict__ u_out) {    // [8192 x 64] bf16
  __shared__ unsigned short tlds[4 * 16 * 72];
  __shared__ float upart[4 * 16 * 68];

  const int tid = threadIdx.x;
  const int lane = tid & 63;
  const int w = tid >> 6;
  const int fr = lane & 15;
  const int quad = lane >> 4;
  const int rowBase = blockIdx.x * 16;

  unsigned short* tl = &tlds[w * 16 * 72];

  bf16x8_t ah0 = *(const bf16x8_t*)&h[(size_t)(rowBase + fr) * 64 + quad * 8];
  bf16x8_t ah1 = *(const bf16x8_t*)&h[(size_t)(rowBase + fr) * 64 + 32 + quad * 8];

  f32x4_t uacc[4];
#pragma unroll
  for (int n = 0; n < 4; n++) uacc[n] = f32x4_t{0.f, 0.f, 0.f, 0.f};

  for (int it = 0; it < 4; ++it) {
    const int cb = w * 256 + it * 64;

    f32x4_t tacc[4];
#pragma unroll
    for (int nt = 0; nt < 4; nt++) {
      const unsigned short* vrow = Vb + (size_t)(cb + nt * 16 + fr) * 64;
      bf16x8_t b0 = *(const bf16x8_t*)&vrow[quad * 8];
      bf16x8_t b1 = *(const bf16x8_t*)&vrow[32 + quad * 8];
      f32x4_t z = {0.f, 0.f, 0.f, 0.f};
      z = __builtin_amdgcn_mfma_f32_16x16x32_bf16(ah0, b0, z, 0, 0, 0);
      tacc[nt] = __builtin_amdgcn_mfma_f32_16x16x32_bf16(ah1, b1, z, 0, 0, 0);
    }

#pragma unroll
    for (int nt = 0; nt < 4; nt++) {
      float bv = bias[cb + nt * 16 + fr];
#pragma unroll
      for (int r = 0; r < 4; r++) {
        float v = tacc[nt][r] + bv;
        v = v > 0.f ? v : 0.f;
        tl[(quad * 4 + r) * 72 + nt * 16 + fr] = f2bf(v);
      }
    }

    {
      int m2 = lane >> 2;
      int kc = (lane & 3) * 16;
      bf16x8_t t0 = *(const bf16x8_t*)&tl[m2 * 72 + kc];
      bf16x8_t t1 = *(const bf16x8_t*)&tl[m2 * 72 + kc + 8];
      unsigned short* ap = act + (size_t)(rowBase + m2) * 1024 + cb + kc;
      *(bf16x8_t*)ap = t0;
      *(bf16x8_t*)(ap + 8) = t1;
    }

#pragma unroll
    for (int ks = 0; ks < 2; ++ks) {
      bf16x8_t at = *(const bf16x8_t*)&tl[fr * 72 + ks * 32 + quad * 8];
#pragma unroll
      for (int n = 0; n < 4; n++) {
        bf16x8_t bu = *(const bf16x8_t*)&Un[(size_t)(n * 16 + fr) * 1024 + cb +
                                            ks * 32 + quad * 8];
        uacc[n] = __builtin_amdgcn_mfma_f32_16x16x32_bf16(at, bu, uacc[n], 0, 0, 0);
      }
    }
  }

  {
    float* up = &upart[w * 16 * 68];
#pragma unroll
    for (int n = 0; n < 4; n++)
#pragma unroll
      for (int r = 0; r < 4; r++)
        up[(quad * 4 + r) * 68 + n * 16 + fr] = uacc[n][r];
  }
  __syncthreads();
  {
    int m = tid >> 4;
    int c0 = (tid & 15) * 4;
    f32x4_t s = {0.f, 0.f, 0.f, 0.f};
#pragma unroll
    for (int wv = 0; wv < 4; wv++)
      s += *(const f32x4_t*)&upart[wv * 16 * 68 + m * 68 + c0];
    u16x4_t o = { f2bf(s[0]), f2bf(s[1]), f2bf(s[2]), f2bf(s[3]) };
    *(u16x4_t*)&u_out[(size_t)(rowBase + m) * 64 + c0] = o;
  }
}

// ---------------------------------------------------------------------------
// Final layer: out = h @ V^T + b (fp32), K = 64, coalesced panel stores.
__global__ __launch_bounds__(256, 2) void k_final(
    const unsigned short* __restrict__ A, const unsigned short* __restrict__ B,
    const float* __restrict__ bias, float* __restrict__ Cout) {
  __shared__ union {
    unsigned short ab[2][128 * 64];   // staging for A,B during MFMA phase
    float pan[2][128 * 33];           // two 128x32 output panels (+1 pad)
  } sm;
  unsigned short* As = sm.ab[0];
  unsigned short* Bs = sm.ab[1];

  const int tid = threadIdx.x;
  const int lane = tid & 63;
  const int w = tid >> 6;
  const int wrow0 = (w & 1) * 64;
  const int wcol0 = (w >> 1) * 64;
  const int rowBase = blockIdx.y * 128;
  const int colBase = blockIdx.x * 128;

  const int rl = lane >> 3;
  const int kbg = (lane & 7) ^ rl;
  const int fr = lane & 15;
  const int quad = lane >> 4;

  f32x4_t acc[4][4];
#pragma unroll
  for (int i = 0; i < 4; i++)
#pragma unroll
    for (int j = 0; j < 4; j++) acc[i][j] = f32x4_t{0.f, 0.f, 0.f, 0.f};

#pragma unroll
  for (int jj = 0; jj < 4; ++jj) {
    int tr = w * 32 + jj * 8 + rl;
    const unsigned short* ga = A + (size_t)(rowBase + tr) * 64 + kbg * 8;
    const unsigned short* gb = B + (size_t)(colBase + tr) * 64 + kbg * 8;
    __builtin_amdgcn_global_load_lds(
        (const __attribute__((address_space(1))) void*)ga,
        (__attribute__((address_space(3))) void*)&As[(w * 32 + jj * 8) * 64],
        16, 0, 0);
    __builtin_amdgcn_global_load_lds(
        (const __attribute__((address_space(1))) void*)gb,
        (__attribute__((address_space(3))) void*)&Bs[(w * 32 + jj * 8) * 64],
        16, 0, 0);
  }
  __syncthreads();

#pragma unroll
  for (int ks = 0; ks < 2; ++ks) {
    bf16x8_t a[4], b[4];
#pragma unroll
    for (int i = 0; i < 4; i++) {
      int m = wrow0 + i * 16 + fr;
      int slot = (ks * 4 + quad) ^ (m & 7);
      a[i] = *(const bf16x8_t*)&As[m * 64 + slot * 8];
    }
#pragma unroll
    for (int j = 0; j < 4; j++) {
      int n = wcol0 + j * 16 + fr;
      int slot = (ks * 4 + quad) ^ (n & 7);
      b[j] = *(const bf16x8_t*)&Bs[n * 64 + slot * 8];
    }
#pragma unroll
    for (int i = 0; i < 4; i++)
#pragma unroll
      for (int j = 0; j < 4; j++)
        acc[i][j] = __builtin_amdgcn_mfma_f32_16x16x32_bf16(a[i], b[j],
                                                            acc[i][j], 0, 0, 0);
  }

  float bv[4];
#pragma unroll
  for (int j = 0; j < 4; j++) bv[j] = bias[colBase + wcol0 + j * 16 + fr];

#pragma unroll
  for (int rp = 0; rp < 2; ++rp) {
    __syncthreads();
    {
      float* P = sm.pan[w >> 1];
#pragma unroll
      for (int jj = 0; jj < 2; ++jj) {
        int j = rp * 2 + jj;
        int colp = jj * 16 + fr;
#pragma unroll
        for (int i = 0; i < 4; i++)
#pragma unroll
          for (int r = 0; r < 4; r++) {
            int row = wrow0 + i * 16 + quad * 4 + r;
            P[row * 33 + colp] = acc[i][j][r] + bv[j];
          }
      }
    }
    __syncthreads();
    {
      int row = tid >> 1;
      int ch = (tid & 1) * 16;
#pragma unroll
      for (int pb = 0; pb < 2; ++pb) {
        const float* Pr = &sm.pan[pb][row * 33 + ch];
        float4 v0 = { Pr[0],  Pr[1],  Pr[2],  Pr[3]  };
        float4 v1 = { Pr[4],  Pr[5],  Pr[6],  Pr[7]  };
        float4 v2 = { Pr[8],  Pr[9],  Pr[10], Pr[11] };
        float4 v3 = { Pr[12], Pr[13], Pr[14], Pr[15] };
        float* out = &Cout[(size_t)(rowBase + row) * 1024 + colBase + pb * 64 +
                           rp * 32 + ch];
        ((float4*)out)[0] = v0;
        ((float4*)out)[1] = v1;
        ((float4*)out)[2] = v2;
        ((float4*)out)[3] = v3;
      }
    }
  }
}

// ---------------------------------------------------------------------------
extern "C" void kernel_launch(void* const* d_in, const int* in_sizes, int n_in,
                              void* d_out, int out_size, void* d_ws,
                              size_t ws_size, hipStream_t stream) {
  const float* x = (const float*)d_in[0];
  const float* Wm[3] = {(const float*)d_in[1], (const float*)d_in[6], (const float*)d_in[11]};
  const float* bm[3] = {(const float*)d_in[2], (const float*)d_in[7], (const float*)d_in[12]};
  const float* U[3]  = {(const float*)d_in[3], (const float*)d_in[8], (const float*)d_in[13]};
  const float* V[3]  = {(const float*)d_in[4], (const float*)d_in[9], (const float*)d_in[14]};
  const float* bs[3] = {(const float*)d_in[5], (const float*)d_in[10], (const float*)d_in[15]};

  char* p = (char*)d_ws;
  unsigned short* xb = (unsigned short*)p;  p += 8192UL * 1024 * 2;
  unsigned short* act = (unsigned short*)p; p += 8192UL * 1024 * 2;
  unsigned short* Wmb[3];
  for (int l = 0; l < 3; l++) { Wmb[l] = (unsigned short*)p; p += 4096UL * 1024 * 2; }
  unsigned short* Ub[3];
  for (int l = 0; l < 3; l++) { Ub[l] = (unsigned short*)p; p += 64UL * 1024 * 2; }
  unsigned short* Vb[3];
  for (int l = 0; l < 3; l++) { Vb[l] = (unsigned short*)p; p += 1024UL * 64 * 2; }
  unsigned short* hb = (unsigned short*)p;  p += 8192UL * 64 * 2;
  unsigned short* ug = (unsigned short*)p;  p += 8192UL * 64 * 2;

  // Dispatch 1: convert Wm0 + U0 (38 MB read) — the only serial conversions
  CvtSeg c0;
  c0.src[0] = Wm[0]; c0.dst[0] = Wmb[0];
  c0.src[1] = U[0];  c0.dst[1] = Ub[0];
  c0.src[2] = U[0];  c0.dst[2] = Ub[0];   // unused (bstart collapse)
  c0.bstart[0] = 0; c0.bstart[1] = 4096; c0.bstart[2] = 4160; c0.bstart[3] = 4160;
  k_cvt<<<4160, 256, 0, stream>>>(c0);

  // Dispatch 2: x cvt + u0 = x @ U0^T, fused (writes xb and ug)
  xu_fused<<<512, 256, 0, stream>>>(x, Ub[0], xb, ug);

  // cvt tables for the work appended to each hyper dispatch (512-thread blocks)
  CvtSeg ch[3];
  ch[0].src[0] = Wm[1]; ch[0].dst[0] = Wmb[1];
  ch[0].src[1] = U[1];  ch[0].dst[1] = Ub[1];
  ch[0].src[2] = V[0];  ch[0].dst[2] = Vb[0];
  ch[0].bstart[0] = 0; ch[0].bstart[1] = 2048; ch[0].bstart[2] = 2080; ch[0].bstart[3] = 2112;
  ch[1].src[0] = Wm[2]; ch[1].dst[0] = Wmb[2];
  ch[1].src[1] = U[2];  ch[1].dst[1] = Ub[2];
  ch[1].src[2] = V[1];  ch[1].dst[2] = Vb[1];
  ch[1].bstart[0] = 0; ch[1].bstart[1] = 2048; ch[1].bstart[2] = 2080; ch[1].bstart[3] = 2112;
  ch[2].src[0] = V[2]; ch[2].dst[0] = Vb[2];
  ch[2].src[1] = V[2]; ch[2].dst[1] = Vb[2];   // unused
  ch[2].src[2] = V[2]; ch[2].dst[2] = Vb[2];   // unused
  ch[2].bstart[0] = 0; ch[2].bstart[1] = 32; ch[2].bstart[2] = 32; ch[2].bstart[3] = 32;

  const int hyperGrid[3] = {512 + 2112, 512 + 2112, 512 + 32};

  const unsigned short* cur = xb;
  for (int l = 0; l < 3; l++) {
    // fused: h = einsum('br,brs->bs', u, cur@Wm^T + bm)  [+ appended cvt]
    k_hyper<<<hyperGrid[l], 512, 0, stream>>>(cur, Wmb[l], ug, bm[l], hb, ch[l]);
    if (l < 2) {
      // act = relu(h@V^T + b); u(next) = act @ U[l+1]^T
      vu_fused<<<512, 256, 0, stream>>>(hb, Vb[l], bs[l], Ub[l + 1], act, ug);
      cur = act;
    } else {
      k_final<<<dim3(8, 64), 256, 0, stream>>>(hb, Vb[2], bs[2], (float*)d_out);
    }
  }
}